// Round 10
// baseline (339.320 us; speedup 1.0000x reference)
//
#include <hip/hip_runtime.h>
#include <hip/hip_bf16.h>

#define HID 256
#define QD 64
#define NSEG 16
#define SLQ 2048
#define SLH 2048

typedef __attribute__((ext_vector_type(8))) short bf16x8;
typedef __attribute__((ext_vector_type(8))) __bf16 bf16x8b;
typedef __attribute__((ext_vector_type(4))) float f32x4;
typedef __attribute__((ext_vector_type(4))) short s16x4;

#define BAR_LDS() asm volatile("s_waitcnt lgkmcnt(0)\n\ts_barrier" ::: "memory")

static __device__ __forceinline__ f32x4 mfma16(bf16x8 a, bf16x8 b, f32x4 c) {
  return __builtin_amdgcn_mfma_f32_16x16x32_bf16(
      __builtin_bit_cast(bf16x8b, a), __builtin_bit_cast(bf16x8b, b), c, 0, 0, 0);
}

static __device__ __forceinline__ short f2bf(float x) {
  union { float f; unsigned u; } v; v.f = x;
  unsigned r = v.u + 0x7fffu + ((v.u >> 16) & 1u);
  return (short)(r >> 16);
}

static __device__ __forceinline__ float bf2f(short s) {
  union { unsigned u; float f; } v;
  v.u = ((unsigned)(unsigned short)s) << 16;
  return v.f;
}

// Fused weight casts: WQ, WK, WV, fc_w -> bf16
__global__ __launch_bounds__(256) void cast4_kernel(const float* __restrict__ s0, short* __restrict__ d0, int n0,
                                                    const float* __restrict__ s1, short* __restrict__ d1, int n1,
                                                    const float* __restrict__ s2, short* __restrict__ d2, int n2,
                                                    const float* __restrict__ s3, short* __restrict__ d3, int n3) {
  int i = blockIdx.x * 256 + threadIdx.x;
  if (i < n0) d0[i] = f2bf(s0[i]);
  int j = i - n0;
  if (j >= 0 && j < n1) d1[j] = f2bf(s1[j]);
  int k = j - n1;
  if (k >= 0 && k < n2) d2[k] = f2bf(s2[k]);
  int l = k - n2;
  if (l >= 0 && l < n3) d3[l] = f2bf(s3[l]);
}

// Merged projections, 32-row tiles -> 2048 blocks = 4 blocks/CU = 16 waves/CU.
// Blocks 0..1023: h-part -> kb (h@WK^T) + vt (WV@h^T, [seg][dv][tok]).
// Blocks 1024..2047: q-part -> qq (q@WQ^T).
// Per wave: m-tile = wave&1 (16 of the 32 rows), n-half = wave>>1.
__global__ __launch_bounds__(256, 4) void proj_kernel(const float* __restrict__ q,
                                                      const float* __restrict__ h,
                                                      const short* __restrict__ wqb,
                                                      const short* __restrict__ wkb,
                                                      const short* __restrict__ wvb,
                                                      short* __restrict__ qq,
                                                      short* __restrict__ kb,
                                                      short* __restrict__ vt) {
  __shared__ short hb[32][264];  // 16.9 KB
  int bid = blockIdx.x;
  bool isq = bid >= 1024;
  int m0 = (isq ? bid - 1024 : bid) * 32;
  const float* src = isq ? q : h;
  // stage 32 rows x 256 cols fp32 -> bf16; fully coalesced
#pragma unroll
  for (int i = 0; i < 8; ++i) {
    int idx = i * 256 + threadIdx.x;
    int row = idx >> 6, col = (idx & 63) * 4;
    f32x4 v = *(const f32x4*)(src + (size_t)(m0 + row) * HID + col);
    s16x4 pk;
#pragma unroll
    for (int j = 0; j < 4; ++j) pk[j] = f2bf(v[j]);
    *(s16x4*)&hb[row][col] = pk;
  }
  __syncthreads();
  int wave = threadIdx.x >> 6, lane = threadIdx.x & 63;
  int quad = lane >> 4, l16 = lane & 15;
  int mt = wave & 1;   // which 16-row tile of the block's 32 rows
  int nh = wave >> 1;  // which n-half

  if (isq) {
    f32x4 acc[2];
#pragma unroll
    for (int n = 0; n < 2; ++n) acc[n] = f32x4{0.f, 0.f, 0.f, 0.f};
#pragma unroll
    for (int ks = 0; ks < 8; ++ks) {
      bf16x8 a = *(const bf16x8*)&hb[mt * 16 + l16][ks * 32 + quad * 8];
#pragma unroll
      for (int n = 0; n < 2; ++n) {
        bf16x8 b = *(const bf16x8*)(wqb + (size_t)((nh * 2 + n) * 16 + l16) * HID + ks * 32 + quad * 8);
        acc[n] = mfma16(a, b, acc[n]);
      }
    }
#pragma unroll
    for (int n = 0; n < 2; ++n)
#pragma unroll
      for (int r = 0; r < 4; ++r)
        qq[(size_t)(m0 + mt * 16 + quad * 4 + r) * QD + (nh * 2 + n) * 16 + l16] = f2bf(acc[n][r]);
  } else {
    f32x4 kacc[2];
    f32x4 vacc[8];
#pragma unroll
    for (int n = 0; n < 2; ++n) kacc[n] = f32x4{0.f, 0.f, 0.f, 0.f};
#pragma unroll
    for (int n = 0; n < 8; ++n) vacc[n] = f32x4{0.f, 0.f, 0.f, 0.f};
#pragma unroll
    for (int ks = 0; ks < 8; ++ks) {
      // same LDS frag: A (h-rows) for K-proj, B (h-cols) for V^T-proj
      bf16x8 a = *(const bf16x8*)&hb[mt * 16 + l16][ks * 32 + quad * 8];
#pragma unroll
      for (int n = 0; n < 2; ++n) {
        bf16x8 b = *(const bf16x8*)(wkb + (size_t)((nh * 2 + n) * 16 + l16) * HID + ks * 32 + quad * 8);
        kacc[n] = mfma16(a, b, kacc[n]);
      }
#pragma unroll
      for (int mv = 0; mv < 8; ++mv) {
        bf16x8 wf = *(const bf16x8*)(wvb + (size_t)((nh * 8 + mv) * 16 + l16) * HID + ks * 32 + quad * 8);
        vacc[mv] = mfma16(wf, a, vacc[mv]);  // D[m=dv][n=tok]
      }
    }
#pragma unroll
    for (int n = 0; n < 2; ++n)
#pragma unroll
      for (int r = 0; r < 4; ++r)
        kb[(size_t)(m0 + mt * 16 + quad * 4 + r) * QD + (nh * 2 + n) * 16 + l16] = f2bf(kacc[n][r]);
    int seg = m0 >> 11;
    int tokl = m0 & 2047;
    short* vs = vt + (size_t)seg * HID * SLH;
#pragma unroll
    for (int mv = 0; mv < 8; ++mv)
#pragma unroll
      for (int r = 0; r < 4; ++r) {
        int dv = nh * 128 + mv * 16 + quad * 4 + r;
        vs[(size_t)dv * SLH + tokl + mt * 16 + l16] = f2bf(vacc[mv][r]);
      }
  }
}

// Flash attention v5 + fused LN1 (byte-identical to passing r9).
__global__ __launch_bounds__(256, 2) void attn_kernel(const short* __restrict__ qq,
                                                      const short* __restrict__ kb,
                                                      const short* __restrict__ vt,
                                                      const float* __restrict__ qres,
                                                      const float* __restrict__ n0w,
                                                      const float* __restrict__ n0b,
                                                      short* __restrict__ xb) {
  __shared__ short p_lds[2][64][136];  // 34.8 KB; reused as o-staging in epilogue
  int wave = threadIdx.x >> 6, lane = threadIdx.x & 63;
  int quad = lane >> 4, l16 = lane & 15;
  int b = blockIdx.x;
  int xcd = b & 7, li = b >> 3;
  int seg = xcd * 2 + (li >> 5);
  int tile = li & 31;
  int qrow0 = seg * SLQ + tile * 64;
  const short* kseg = kb + (size_t)seg * SLH * QD;
  const short* vseg = vt + (size_t)seg * HID * SLH;

  const short* qbase = qq + (size_t)(qrow0 + wave * 16 + l16) * QD + quad * 8;
  bf16x8 qf0 = *(const bf16x8*)qbase;
  bf16x8 qf1 = *(const bf16x8*)(qbase + 32);

  f32x4 o[4][4];
#pragma unroll
  for (int m = 0; m < 4; ++m)
#pragma unroll
    for (int n = 0; n < 4; ++n) o[m][n] = f32x4{0.f, 0.f, 0.f, 0.f};
  float lsum = 0.f;
  const float cexp = 0.125f * 1.44269504f;  // scale * log2(e)
  bf16x8 kpre[8][2];

#define LOADK(IT)                                                               \
  {                                                                             \
    int k0 = (IT) * 128;                                                        \
    _Pragma("unroll") for (int t = 0; t < 8; ++t) {                             \
      const short* kp = kseg + (size_t)(k0 + t * 16 + l16) * QD + quad * 8;     \
      kpre[t][0] = *(const bf16x8*)kp;                                          \
      kpre[t][1] = *(const bf16x8*)(kp + 32);                                   \
    }                                                                           \
  }

#define S_PHASE(BUF)                                                            \
  {                                                                             \
    f32x4 s[8];                                                                 \
    _Pragma("unroll") for (int t = 0; t < 8; ++t) {                             \
      f32x4 a = f32x4{0.f, 0.f, 0.f, 0.f};                                      \
      a = mfma16(kpre[t][0], qf0, a);                                           \
      a = mfma16(kpre[t][1], qf1, a);                                           \
      s[t] = a;                                                                 \
    }                                                                           \
    _Pragma("unroll") for (int t = 0; t < 8; ++t) {                             \
      float p0 = __builtin_amdgcn_exp2f(s[t][0] * cexp);                        \
      float p1 = __builtin_amdgcn_exp2f(s[t][1] * cexp);                        \
      float p2 = __builtin_amdgcn_exp2f(s[t][2] * cexp);                        \
      float p3 = __builtin_amdgcn_exp2f(s[t][3] * cexp);                        \
      lsum += (p0 + p1) + (p2 + p3);                                            \
      s16x4 pk;                                                                 \
      pk[0] = f2bf(p0); pk[1] = f2bf(p1); pk[2] = f2bf(p2); pk[3] = f2bf(p3);   \
      *(s16x4*)&p_lds[BUF][wave * 16 + l16][t * 16 + quad * 4] = pk;            \
    }                                                                           \
  }

#define PV_PHASE(IT, BUF)                                                       \
  {                                                                             \
    int k0 = (IT) * 128;                                                        \
    _Pragma("unroll") for (int ks = 0; ks < 4; ++ks) {                          \
      bf16x8 pf[4];                                                             \
      _Pragma("unroll") for (int m = 0; m < 4; ++m)                             \
        pf[m] = *(const bf16x8*)&p_lds[BUF][m * 16 + l16][ks * 32 + quad * 8];  \
      _Pragma("unroll") for (int n = 0; n < 4; ++n) {                           \
        const short* vp = vseg + (size_t)(wave * 64 + n * 16 + l16) * SLH +     \
                          k0 + ks * 32 + quad * 8;                              \
        bf16x8 vf = *(const bf16x8*)vp;                                         \
        _Pragma("unroll") for (int m = 0; m < 4; ++m)                           \
          o[m][n] = mfma16(pf[m], vf, o[m][n]);                                 \
      }                                                                         \
    }                                                                           \
  }

  LOADK(0)
  S_PHASE(0)
  LOADK(1)
  BAR_LDS();
#pragma unroll 1
  for (int it = 1; it < 16; ++it) {
    S_PHASE(it & 1)
    if (it < 15) LOADK(it + 1)
    PV_PHASE(it - 1, (it - 1) & 1)
    BAR_LDS();
  }
  PV_PHASE(15, 1)

  lsum += __shfl_xor(lsum, 16);
  lsum += __shfl_xor(lsum, 32);
  float linv = 1.f / lsum;

  BAR_LDS();
  short (*ob)[264] = (short(*)[264]) & p_lds[0][0][0];
#pragma unroll
  for (int m = 0; m < 4; ++m)
#pragma unroll
    for (int n = 0; n < 4; ++n)
#pragma unroll
      for (int r = 0; r < 4; ++r)
        ob[m * 16 + quad * 4 + r][wave * 64 + n * 16 + l16] = f2bf(o[m][n][r]);
  BAR_LDS();

  {
    int row = wave * 16 + l16;
    float y[64];
    float s1 = 0.f, s2 = 0.f;
    const float* qp = qres + (size_t)(qrow0 + row) * HID + quad * 64;
#pragma unroll
    for (int k = 0; k < 8; ++k) {
      bf16x8 ov = *(const bf16x8*)&ob[row][quad * 64 + k * 8];
      f32x4 qa = *(const f32x4*)(qp + k * 8);
      f32x4 qb = *(const f32x4*)(qp + k * 8 + 4);
#pragma unroll
      for (int j = 0; j < 4; ++j) {
        float yv = qa[j] + bf2f(ov[j]) * linv;
        y[k * 8 + j] = yv;
        s1 += yv; s2 += yv * yv;
      }
#pragma unroll
      for (int j = 0; j < 4; ++j) {
        float yv = qb[j] + bf2f(ov[4 + j]) * linv;
        y[k * 8 + 4 + j] = yv;
        s1 += yv; s2 += yv * yv;
      }
    }
    s1 += __shfl_xor(s1, 16); s2 += __shfl_xor(s2, 16);
    s1 += __shfl_xor(s1, 32); s2 += __shfl_xor(s2, 32);
    float mean = s1 * (1.f / HID);
    float var = s2 * (1.f / HID) - mean * mean;
    float rstd = rsqrtf(var + 1e-5f);
    short* xp = xb + (size_t)(qrow0 + row) * HID + quad * 64;
#pragma unroll
    for (int k = 0; k < 8; ++k) {
      f32x4 wa = *(const f32x4*)(n0w + quad * 64 + k * 8);
      f32x4 wb = *(const f32x4*)(n0w + quad * 64 + k * 8 + 4);
      f32x4 ba = *(const f32x4*)(n0b + quad * 64 + k * 8);
      f32x4 bb = *(const f32x4*)(n0b + quad * 64 + k * 8 + 4);
      s16x4 o0, o1;
#pragma unroll
      for (int j = 0; j < 4; ++j) {
        o0[j] = f2bf((y[k * 8 + j] - mean) * rstd * wa[j] + ba[j]);
        o1[j] = f2bf((y[k * 8 + 4 + j] - mean) * rstd * wb[j] + bb[j]);
      }
      *(s16x4*)(xp + k * 8) = o0;
      *(s16x4*)(xp + k * 8 + 4) = o1;
    }
  }
#undef LOADK
#undef S_PHASE
#undef PV_PHASE
}

// out = LN(x + relu(x@fc_w^T + fc_b)); 32-row tiles -> 1024 blocks = 4/CU =
// 16 waves/CU. Wave: m-tile = wave&1, n-half = wave>>1 (128 cols, acc[8]).
// LN epilogue intra-wave: y staged bf16 to LDS, lane owns (row=lane&7,
// chunk=lane>>3), shfl_xor 8/16/32 reduces the 8 chunks of a row.
__global__ __launch_bounds__(256, 4) void fc_ln_kernel(const short* __restrict__ xb,
                                                       const short* __restrict__ fwb,
                                                       const float* __restrict__ fcb,
                                                       const float* __restrict__ w1,
                                                       const float* __restrict__ b1,
                                                       float* __restrict__ out) {
  __shared__ short xt[32][264];
  __shared__ short yt[32][264];
  int m0 = blockIdx.x * 32;
  // stage 32 rows x 256 bf16 (16 KB), coalesced
#pragma unroll
  for (int i = 0; i < 4; ++i) {
    int idx = i * 256 + threadIdx.x;
    int row = idx >> 5, col = (idx & 31) * 8;
    *(bf16x8*)&xt[row][col] = *(const bf16x8*)(xb + (size_t)(m0 + row) * HID + col);
  }
  __syncthreads();
  int wave = threadIdx.x >> 6, lane = threadIdx.x & 63;
  int quad = lane >> 4, l16 = lane & 15;
  int mt = wave & 1, nh = wave >> 1;
  f32x4 acc[8];
#pragma unroll
  for (int n = 0; n < 8; ++n) acc[n] = f32x4{0.f, 0.f, 0.f, 0.f};
#pragma unroll
  for (int ks = 0; ks < 8; ++ks) {
    bf16x8 a = *(const bf16x8*)&xt[mt * 16 + l16][ks * 32 + quad * 8];
#pragma unroll
    for (int n = 0; n < 8; ++n) {
      bf16x8 b = *(const bf16x8*)(fwb + (size_t)((nh * 8 + n) * 16 + l16) * HID + ks * 32 + quad * 8);
      acc[n] = mfma16(a, b, acc[n]);
    }
  }
  // y = x + relu(acc + bias) -> yt (bf16)
#pragma unroll
  for (int n = 0; n < 8; ++n) {
    int col = (nh * 8 + n) * 16 + l16;
    float bv = fcb[col];
#pragma unroll
    for (int r = 0; r < 4; ++r) {
      int lrow = mt * 16 + quad * 4 + r;
      float hres = fmaxf(acc[n][r] + bv, 0.f);
      yt[lrow][col] = f2bf(bf2f(xt[lrow][col]) + hres);
    }
  }
  __syncthreads();
  // LN: lane owns row = wave*8 + (lane&7), chunk = lane>>3 (32 cols)
  {
    int row = wave * 8 + (lane & 7);
    int ch = lane >> 3;
    float y[32];
    float s = 0.f, s2 = 0.f;
#pragma unroll
    for (int k = 0; k < 4; ++k) {
      bf16x8 v = *(const bf16x8*)&yt[row][ch * 32 + k * 8];
#pragma unroll
      for (int j = 0; j < 8; ++j) {
        float yv = bf2f(v[j]);
        y[k * 8 + j] = yv;
        s += yv; s2 += yv * yv;
      }
    }
    s += __shfl_xor(s, 8);  s2 += __shfl_xor(s2, 8);
    s += __shfl_xor(s, 16); s2 += __shfl_xor(s2, 16);
    s += __shfl_xor(s, 32); s2 += __shfl_xor(s2, 32);
    float mean = s * (1.f / HID);
    float var = s2 * (1.f / HID) - mean * mean;
    float rstd = rsqrtf(var + 1e-5f);
    float* op = out + (size_t)(m0 + row) * HID + ch * 32;
#pragma unroll
    for (int k = 0; k < 8; ++k) {
      f32x4 wv = *(const f32x4*)(w1 + ch * 32 + k * 4);
      f32x4 bv = *(const f32x4*)(b1 + ch * 32 + k * 4);
      f32x4 ov;
#pragma unroll
      for (int j = 0; j < 4; ++j) ov[j] = (y[k * 4 + j] - mean) * rstd * wv[j] + bv[j];
      *(f32x4*)(op + k * 4) = ov;
    }
  }
}

extern "C" void kernel_launch(void* const* d_in, const int* in_sizes, int n_in,
                              void* d_out, int out_size, void* d_ws, size_t ws_size,
                              hipStream_t stream) {
  const float* q = (const float*)d_in[0];
  const float* h = (const float*)d_in[1];
  const float* WQ = (const float*)d_in[2];
  const float* WK = (const float*)d_in[3];
  const float* WV = (const float*)d_in[4];
  const float* fc_w = (const float*)d_in[5];
  const float* fc_b = (const float*)d_in[6];
  const float* n0w = (const float*)d_in[7];
  const float* n0b = (const float*)d_in[8];
  const float* n1w = (const float*)d_in[9];
  const float* n1b = (const float*)d_in[10];

  char* ws = (char*)d_ws;
  short* qq = (short*)(ws);                            //  4 MB  [0,4)
  short* kb = (short*)(ws + ((size_t)4 << 20));        //  4 MB  [4,8)
  short* vt = (short*)(ws + ((size_t)8 << 20));        // 16 MB  [8,24)
  short* xb = (short*)(ws + ((size_t)24 << 20));       // 16 MB  [24,40)
  short* wqb = (short*)(ws + ((size_t)40 << 20));
  short* wkb = (short*)(ws + ((size_t)40 << 20) + 32 * 1024);
  short* wvb = (short*)(ws + ((size_t)40 << 20) + 64 * 1024);
  short* fwb = (short*)(ws + ((size_t)40 << 20) + 192 * 1024);

  cast4_kernel<<<640, 256, 0, stream>>>(WQ, wqb, QD * HID, WK, wkb, QD * HID,
                                        WV, wvb, HID * HID, fc_w, fwb, HID * HID);
  proj_kernel<<<2048, 256, 0, stream>>>(q, h, wqb, wkb, wvb, qq, kb, vt);
  attn_kernel<<<512, 256, 0, stream>>>(qq, kb, vt, q, n0w, n0b, xb);
  fc_ln_kernel<<<1024, 256, 0, stream>>>(xb, fwb, fc_b, n1w, n1b, (float*)d_out);
}